// Round 15
// baseline (345.995 us; speedup 1.0000x reference)
//
#include <hip/hip_runtime.h>

#define T_LEN 1024
#define P_DIM 32
#define HOME_IDX 0
#define NCHUNK 32
#define CHUNK 32

// One wave (lanes 0-63) per batch; 1024 threads/block exist only for the
// parallel chunked backtrack (waves 1-15 sleep at the post-loop barrier).
//
// THIS round: remove the value shfl_xor from the serial chain entirely via
// max-distribution. Rounding is monotone, so fmax(a,b)+c == fmax(a+c,b+c)
// bit-exactly in VALUE (+-0-sign differences cannot affect comparisons or
// sums-then-comparisons, hence never the paths). So each half writes a
// PARTIAL to LDS:
//     w_h[p] = fmax(bv_h, vx_h) + Ut,  vx_0 = is_home ? NEG : v0, vx_1 = NEG
// and the cross-half combine happens inside the NEXT step's candidates:
//     c[j] = fmax(w0[qj] + A[qj][p], w1[qj] + A[qj][p])  ==  dn1[qj] + A
// (home rule dn1 = v1 + Ut and the strict v1>v0 select both verified
// bit-equal under this form; q=0's NEG absorption preserved.)
//
// The value chain per step: cands -> max3 tree -> w -> ds_write -> 8 uniform
// ds_read_b128. ZERO cross-lane ops on the chain. shfl(bv)/shfl(ia) feed
// only the r14-PROVEN two-stage psi pipeline (stage A: scan step t-1's cands
// vs its LOCAL bv; stage B: combine + psi write for step t-2), issued AFTER
// the reads so they ride the DS pipe in pure slack. cond moves to stage B:
// cond2 = (fmax(bv2,ovv2) > v02) || is_home, with v0 pipelined.
//
// Exactness notes (harness-verified across rounds + the distribution proof):
//  * NEG = finfo(f32).min/4; NEG + A == NEG -> v=0 slice collapses; a0 = 0.
//  * strict v1 > v0; psi byte = cond ? (a1|32) : 0.
//  * local scan: CP[j]==bvp descending-j -> first local index; combine
//    a1 = bv2>ovv2 ? ia2 : io2, tie -> min (half 0 owns q<16) => first-index.
//  * delta0h update order preserved: (delta0h + A00) + (u[t,0] + bias0).
//  * final delta_T[p] = fmax(w_own, shfl_xor(w_own,32)).
//
// Backtrack (PROVEN round 4): phases 1-3 verbatim.

__launch_bounds__(1024, 1)
__global__ void crf_viterbi_kernel(const float* __restrict__ U,
                                   const float* __restrict__ A,
                                   const float* __restrict__ bias,
                                   int* __restrict__ out)
{
    __shared__ __align__(16) float sw[2 * P_DIM];         // 256 B partials
    __shared__ unsigned char spsi[(T_LEN - 1) * P_DIM];   // 32736 B
    __shared__ unsigned char Mmap[NCHUNK * P_DIM];        // chunk maps
    __shared__ unsigned char ent[NCHUNK];                 // chunk entry states
    __shared__ int last_p_sh;

    const int tid = threadIdx.x;
    const int b   = blockIdx.x;
    int* __restrict__ outb = out + (size_t)b * T_LEN;

    if (tid < 64) {
        const int lane = tid;
        const int p    = lane & 31;
        const int h    = lane >> 5;
        const float NEG = -(3.4028234663852886e38f / 4.0f);

        // A fragment: A[q][p] for q = 16*h + j
        float Areg[16];
#pragma unroll
        for (int j = 0; j < 16; ++j)
            Areg[j] = A[(16 * h + j) * P_DIM + p];
        const float A0p    = A[p];        // A[HOME][p]
        const float A00    = A[0];        // A[HOME][HOME]
        const float bias_p = bias[p];
        const float bias0  = bias[0];
        const int   q0     = h << 4;      // first q of this half
        const bool  is_home = (p == HOME_IDX);

        const float4* __restrict__ sw4 = (const float4*)sw;
        const float* __restrict__ Ub = U + (size_t)b * T_LEN * P_DIM;

        // t = 0 init
        const float u00 = Ub[p] + bias_p;
        const float dinit = is_home ? NEG : u00;   // delta[0], v=1 slice
        float delta0h = Ub[HOME_IDX] + bias0;      // v=0 slice at HOME

        // Prefetch ring, depth 4. Row t lives in slot (t-1)&3.
        float L0 = Ub[1 * P_DIM + p];
        float L1 = Ub[2 * P_DIM + p];
        float L2 = Ub[3 * P_DIM + p];
        float L3 = Ub[4 * P_DIM + p];

        float Ut_n = L0 + bias_p;          // for t = 1
        float u0_n = __shfl(Ut_n, 0);      // u[t,0] + bias0, broadcast

        // Stage initial partials: w0 = delta[0], w1 = NEG  (fmax(w0,w1)=delta[0];
        // fused cands at t=1 reproduce delta[0][q]+A exactly, incl. q=0's NEG).
        sw[h * 32 + p] = h ? NEG : dinit;
        float4 R0 = sw4[4 * h + 0], R1 = sw4[4 * h + 1];
        float4 R2 = sw4[4 * h + 2], R3 = sw4[4 * h + 3];
        float4 R4 = sw4[8 + 4 * h + 0], R5 = sw4[8 + 4 * h + 1];
        float4 R6 = sw4[8 + 4 * h + 2], R7 = sw4[8 + 4 * h + 3];

        // psi pipeline state
        float cA[16], cB[16];
        float bvp = 0.f, ovvp = 0.f, bv2 = 0.f, ovv2 = 0.f;
        float v0p = 0.f, v02 = 0.f;
        int   ia2 = 0, io2 = 0;
        float w_keep = 0.f;

#define STEP(t, F1, F2, CC, CP, Lc, Lr) do {                                   \
    const float Ut  = Ut_n;                                                    \
    const float u0c = u0_n;                                                    \
    const float v0  = delta0h + A0p;    /* pre-update delta0h */               \
    /* fused candidates: fmax(w0[q]+A, w1[q]+A) == dn1_prev[q] + A (bit) */    \
    CC[0]  = fmaxf(R0.x + Areg[0],  R4.x + Areg[0]);                           \
    CC[1]  = fmaxf(R0.y + Areg[1],  R4.y + Areg[1]);                           \
    CC[2]  = fmaxf(R0.z + Areg[2],  R4.z + Areg[2]);                           \
    CC[3]  = fmaxf(R0.w + Areg[3],  R4.w + Areg[3]);                           \
    CC[4]  = fmaxf(R1.x + Areg[4],  R5.x + Areg[4]);                           \
    CC[5]  = fmaxf(R1.y + Areg[5],  R5.y + Areg[5]);                           \
    CC[6]  = fmaxf(R1.z + Areg[6],  R5.z + Areg[6]);                           \
    CC[7]  = fmaxf(R1.w + Areg[7],  R5.w + Areg[7]);                           \
    CC[8]  = fmaxf(R2.x + Areg[8],  R6.x + Areg[8]);                           \
    CC[9]  = fmaxf(R2.y + Areg[9],  R6.y + Areg[9]);                           \
    CC[10] = fmaxf(R2.z + Areg[10], R6.z + Areg[10]);                          \
    CC[11] = fmaxf(R2.w + Areg[11], R6.w + Areg[11]);                          \
    CC[12] = fmaxf(R3.x + Areg[12], R7.x + Areg[12]);                          \
    CC[13] = fmaxf(R3.y + Areg[13], R7.y + Areg[13]);                          \
    CC[14] = fmaxf(R3.z + Areg[14], R7.z + Areg[14]);                          \
    CC[15] = fmaxf(R3.w + Areg[15], R7.w + Areg[15]);                          \
    const float g0 = fmaxf(fmaxf(CC[0],  CC[1]),  CC[2]);                      \
    const float g1 = fmaxf(fmaxf(CC[3],  CC[4]),  CC[5]);                      \
    const float g2 = fmaxf(fmaxf(CC[6],  CC[7]),  CC[8]);                      \
    const float g3 = fmaxf(fmaxf(CC[9],  CC[10]), CC[11]);                     \
    const float g4 = fmaxf(fmaxf(CC[12], CC[13]), CC[14]);                     \
    const float h0 = fmaxf(fmaxf(g0, g1), g2);                                 \
    const float h1 = fmaxf(fmaxf(g3, g4), CC[15]);                             \
    const float bv = fmaxf(h0, h1);                                            \
    /* partial write: half 0 folds the v0 path (NEG at home), half 1 pure */   \
    const float vx = h ? NEG : (is_home ? NEG : v0);                           \
    const float w  = fmaxf(bv, vx) + Ut;                                       \
    delta0h = (delta0h + A00) + u0c;                                           \
    sw[h * 32 + p] = w;                            /* ds_write (chain) */      \
    R0 = sw4[4 * h + 0]; R1 = sw4[4 * h + 1];      /* 8 reads (chain) */       \
    R2 = sw4[4 * h + 2]; R3 = sw4[4 * h + 3];                                  \
    R4 = sw4[8 + 4 * h + 0]; R5 = sw4[8 + 4 * h + 1];                          \
    R6 = sw4[8 + 4 * h + 2]; R7 = sw4[8 + 4 * h + 3];                          \
    /* ---- psi pipeline (pure slack; shfls ride the DS pipe after reads) */   \
    int ia1 = 0, io1 = 0;                                                      \
    if (F1) {   /* stage A: scan step t-1's cands vs its LOCAL bvp */          \
        ia1 = q0 + 15;                                                         \
        _Pragma("unroll")                                                      \
        for (int j = 14; j >= 0; --j)                                          \
            if (CP[j] == bvp) ia1 = q0 + j;                                    \
        io1 = __shfl_xor(ia1, 32);                                             \
    }                                                                          \
    const float ovvc = __shfl_xor(bv, 32);                                     \
    if (F2) {   /* stage B: combine + psi write for step t-2 (zero stall) */   \
        const float v1_2 = fmaxf(bv2, ovv2);                                   \
        const bool  cond2 = (v1_2 > v02) || is_home;                           \
        const int amin = (ia2 < io2) ? ia2 : io2;                              \
        int a1 = (bv2 > ovv2) ? ia2 : io2;                                     \
        a1 = (bv2 == ovv2) ? amin : a1;                                        \
        spsi[(size_t)((t) - 3) * P_DIM + p] =                                  \
            (unsigned char)(cond2 ? (a1 | 32) : 0);                            \
    }                                                                          \
    /* tail glue fills part of the read latency */                             \
    Ut_n = (Lc) + bias_p;                                                      \
    u0_n = __shfl(Ut_n, 0);                                                    \
    { int tn = (t) + 4; if (tn > T_LEN - 1) tn = T_LEN - 1;                    \
      (Lr) = Ub[(size_t)tn * P_DIM + p]; }                                     \
    /* rotate pipeline */                                                      \
    bv2 = bvp; ovv2 = ovvp; v02 = v0p;                                         \
    ia2 = ia1; io2 = io1;                                                      \
    bvp = bv; ovvp = ovvc; v0p = v0;                                           \
    w_keep = w;                                                                \
} while (0)

        STEP(1, 0, 0, cA, cB, L1, L0);
        STEP(2, 1, 0, cB, cA, L2, L1);
        STEP(3, 1, 1, cA, cB, L3, L2);
        for (int t = 4; t <= T_LEN - 4; t += 4) {
            STEP(t + 0, 1, 1, cB, cA, L0, L3);
            STEP(t + 1, 1, 1, cA, cB, L1, L0);
            STEP(t + 2, 1, 1, cB, cA, L2, L1);
            STEP(t + 3, 1, 1, cA, cB, L3, L2);
        }
#undef STEP

        // Epilogue: flush pending psi stages.
        {   // step T-2 = 1022 (depth-2 slot after the final rotate)
            const float v1_2 = fmaxf(bv2, ovv2);
            const bool  cond2 = (v1_2 > v02) || is_home;
            const int amin = (ia2 < io2) ? ia2 : io2;
            int a1 = (bv2 > ovv2) ? ia2 : io2;
            a1 = (bv2 == ovv2) ? amin : a1;
            spsi[(size_t)(T_LEN - 3) * P_DIM + p] =
                (unsigned char)(cond2 ? (a1 | 32) : 0);
        }
        {   // step T-1 = 1023 (its candidates live in cA after the last STEP)
            int ia = q0 + 15;
#pragma unroll
            for (int j = 14; j >= 0; --j)
                if (cA[j] == bvp) ia = q0 + j;
            const int oia  = __shfl_xor(ia, 32);
            const float v1p = fmaxf(bvp, ovvp);
            const bool  condp = (v1p > v0p) || is_home;
            const int amin = (ia < oia) ? ia : oia;
            int a1 = (bvp > ovvp) ? ia : oia;
            a1 = (bvp == ovvp) ? amin : a1;
            spsi[(size_t)(T_LEN - 2) * P_DIM + p] =
                (unsigned char)(condp ? (a1 | 32) : 0);
        }

        // Final delta_T[p] = fmax(w_own, w_other-half); then proven butterfly.
        const float ow = __shfl_xor(w_keep, 32);
        const float delta1 = fmaxf(w_keep, ow);
        float mv = delta1;
        int   mi = p;
#pragma unroll
        for (int m = 16; m >= 1; m >>= 1) {
            float ov = __shfl_xor(mv, m);
            int   oi = __shfl_xor(mi, m);
            bool take = (ov > mv) || ((ov == mv) && (oi < mi));
            mv = take ? ov : mv;
            mi = take ? oi : mi;
        }
        if (lane == 0) {
            outb[T_LEN - 1] = mi;
            last_p_sh = mi;
        }
    }

    __syncthreads();   // psi + last_p visible to all 16 waves

    // Phase 1: per-chunk maps. Chunk c covers backsteps i in
    // [32c, min(32c+32, 1023)). Thread (c = tid>>5, pp = tid&31) walks from
    // hypothetical entry (pp, v=1).
    {
        const int c  = tid >> 5;
        const int pp = tid & 31;
        const int i_hi = min((c + 1) * CHUNK, T_LEN - 1);
        const int i_lo = c * CHUNK;
        int y = pp, v = 1;
        for (int i = i_hi - 1; i >= i_lo; --i) {
            const int bt = spsi[i * P_DIM + y];
            const int py = v ? (bt & 31) : 0;
            const int nv = v ? ((bt >> 5) & 1) : 0;
            y = py; v = nv;
        }
        Mmap[c * P_DIM + pp] = (unsigned char)(y | (v << 5));
    }
    __syncthreads();

    // Phase 2: compose maps from the top to get each chunk's true entry state.
    if (tid == 0) {
        int y = last_p_sh, v = 1;
        for (int c = NCHUNK - 1; c >= 0; --c) {
            ent[c] = (unsigned char)(y | (v << 5));
            if (v) {
                const int m = Mmap[c * P_DIM + y];
                y = m & 31;
                v = (m >> 5) & 1;
            } else {
                y = 0; v = 0;
            }
        }
    }
    __syncthreads();

    // Phase 3: 32 lanes re-walk their chunk from the true entry, emitting out.
    if (tid < NCHUNK) {
        const int c = tid;
        const int i_hi = min((c + 1) * CHUNK, T_LEN - 1);
        const int i_lo = c * CHUNK;
        const int e = ent[c];
        int y = e & 31;
        int v = (e >> 5) & 1;
        for (int i = i_hi - 1; i >= i_lo; --i) {
            const int bt = spsi[i * P_DIM + y];
            const int py = v ? (bt & 31) : 0;
            const int nv = v ? ((bt >> 5) & 1) : 0;
            outb[i] = py;
            y = py; v = nv;
        }
    }
}

extern "C" void kernel_launch(void* const* d_in, const int* in_sizes, int n_in,
                              void* d_out, int out_size, void* d_ws, size_t ws_size,
                              hipStream_t stream) {
    const float* U    = (const float*)d_in[0];   // (B, T, P) f32
    const float* A    = (const float*)d_in[1];   // (P, P)    f32
    const float* bias = (const float*)d_in[2];   // (P,)      f32
    int* out = (int*)d_out;                      // (B, T)    int32

    const int B = in_sizes[0] / (T_LEN * P_DIM);
    crf_viterbi_kernel<<<B, 1024, 0, stream>>>(U, A, bias, out);
}